// Round 1
// baseline (351.621 us; speedup 1.0000x reference)
//
#include <hip/hip_runtime.h>

typedef unsigned short u16;
typedef __bf16 bf16x8 __attribute__((ext_vector_type(8)));
typedef float f32x4 __attribute__((ext_vector_type(4)));

#define MFMA(a, b, c) __builtin_amdgcn_mfma_f32_16x16x32_bf16(a, b, c, 0, 0, 0)

// Problem constants (fixed by setup_inputs): B=4, H=64, W=128, D=128, NS=2,
// hh=32, ww=64, sh=16, sw=32, L=2048, 16 windows, 32768 total rows.

__device__ __forceinline__ u16 f2b(float f) {
  unsigned u = __builtin_bit_cast(unsigned, f);
  u += 0x7fffu + ((u >> 16) & 1u);
  return (u16)(u >> 16);
}

// ---------------- workspace layout (bytes) ----------------
// phase1: qw@0, kw@8M, vbuf@16M (windowed V, transposed [g][d][tok])
// phase2: attn_out@32M
// phase4: hidden@0 (reuses dead qkv region, 64MB)
// persistent: srcb@64M, msg1@72M, weights@80M   -> needs ~81MB ws
#define QW_OFF   (size_t)(0)
#define KW_OFF   (size_t)(8u << 20)
#define VBUF_OFF (size_t)(16u << 20)
#define AO_OFF   (size_t)(32u << 20)
#define HID_OFF  (size_t)(0)
#define SRCB_OFF (size_t)(64u << 20)
#define MSG1_OFF (size_t)(72u << 20)
#define WQT_OFF  (size_t)(80u << 20)
#define WKT_OFF  (WQT_OFF + 32768)
#define WVT_OFF  (WQT_OFF + 65536)
#define WMT_OFF  (WQT_OFF + 98304)
#define W1T_OFF  (WQT_OFF + 131072)   // 1024x256 bf16 = 512KB
#define W2T_OFF  (WQT_OFF + 655360)   // 128x1024 bf16 = 256KB

// ---------------- kernel 0: transpose weights to bf16 [n][k] ----------------
__global__ void k_prep(const float* __restrict__ wq, const float* __restrict__ wk,
                       const float* __restrict__ wv, const float* __restrict__ wm,
                       const float* __restrict__ w1, const float* __restrict__ w2,
                       u16* __restrict__ wqt, u16* __restrict__ wkt,
                       u16* __restrict__ wvt, u16* __restrict__ wmt,
                       u16* __restrict__ w1t, u16* __restrict__ w2t) {
  int t = blockIdx.x * 256 + threadIdx.x;
  if (t < 65536) {
    int m = t >> 14, loc = t & 16383;
    int n = loc >> 7, k = loc & 127;
    const float* s = (m == 0) ? wq : (m == 1) ? wk : (m == 2) ? wv : wm;
    u16* d = (m == 0) ? wqt : (m == 1) ? wkt : (m == 2) ? wvt : wmt;
    d[n * 128 + k] = f2b(s[k * 128 + n]);
  } else if (t < 65536 + 262144) {
    int loc = t - 65536;
    int n = loc >> 8, k = loc & 255;            // W1: (256,1024) -> [n][k=256]
    w1t[n * 256 + k] = f2b(w1[k * 1024 + n]);
  } else if (t < 65536 + 262144 + 131072) {
    int loc = t - 327680;
    int n = loc >> 10, k = loc & 1023;          // W2: (1024,128) -> [n][k=1024]
    w2t[n * 1024 + k] = f2b(w2[k * 128 + n]);
  }
}

// ---------------- kernel 1: QKV projection, scatter to window layout ----------------
// Windowed token t: g=t>>11 (g=b*4+wi*2+wj), p=t&2047 (p=i*64+j).
// Source pixel: y=(wi*32+i+16)&63, x=(wj*64+j+32)&127  (roll fused).
// qw/kw: [g][p][d] bf16.  vbuf: [g][d][p] bf16 (transposed for PV B-operand).
__global__ __launch_bounds__(256, 2)
void k_qkv(const float* __restrict__ src,
           const u16* __restrict__ wtq, const u16* __restrict__ wtk, const u16* __restrict__ wtv,
           u16* __restrict__ qw, u16* __restrict__ kw, u16* __restrict__ vbuf,
           u16* __restrict__ srcb) {
  __shared__ __align__(16) u16 At[64 * 136];
  __shared__ __align__(16) u16 Bt[128 * 136];
  const int tid = threadIdx.x, bid = blockIdx.x;
  const int lane = tid & 63, wid = tid >> 6;
  const int l15 = lane & 15, quad = lane >> 4;

  {  // stage A tile (64 windowed rows x 128) + write srcb at original rows
    const int row = tid >> 2, part = tid & 3;
    const int t = bid * 64 + row;
    const int g = t >> 11, p = t & 2047;
    const int b = g >> 2, wi = (g >> 1) & 1, wj = g & 1;
    const int ii = p >> 6, jj = p & 63;
    const int y = (wi * 32 + ii + 16) & 63;
    const int x = (wj * 64 + jj + 32) & 127;
    const int srow = b * 8192 + y * 128 + x;
    const float4* sp = (const float4*)(src + srow * 128) + part * 8;
    u16* lp = &At[row * 136 + part * 32];
    u16* gp = srcb + srow * 128 + part * 32;
#pragma unroll
    for (int q = 0; q < 8; ++q) {
      float4 v = sp[q];
      ushort4 h = make_ushort4(f2b(v.x), f2b(v.y), f2b(v.z), f2b(v.w));
      *(ushort4*)(lp + q * 4) = h;
      *(ushort4*)(gp + q * 4) = h;
    }
  }
  __syncthreads();

  bf16x8 afrag[4];
  const int arow = wid * 16 + l15;
#pragma unroll
  for (int kk = 0; kk < 4; ++kk)
    afrag[kk] = *(const bf16x8*)&At[arow * 136 + kk * 32 + quad * 8];

  const f32x4 fz = {0.f, 0.f, 0.f, 0.f};
#pragma unroll 1
  for (int m = 0; m < 3; ++m) {
    const u16* wp = (m == 0) ? wtq : (m == 1) ? wtk : wtv;
    {  // stage B: weight [n][k] 128x128 bf16
      const int n = tid >> 1, half = tid & 1;
      const uint4* sp = (const uint4*)(wp + n * 128 + half * 64);
      uint4* dp = (uint4*)&Bt[n * 136 + half * 64];
#pragma unroll
      for (int q = 0; q < 8; ++q) dp[q] = sp[q];
    }
    __syncthreads();
    f32x4 acc[8];
#pragma unroll
    for (int nt = 0; nt < 8; ++nt) acc[nt] = fz;
#pragma unroll
    for (int kk = 0; kk < 4; ++kk) {
#pragma unroll
      for (int nt = 0; nt < 8; ++nt) {
        bf16x8 bfr = *(const bf16x8*)&Bt[(nt * 16 + l15) * 136 + kk * 32 + quad * 8];
        acc[nt] = MFMA(afrag[kk], bfr, acc[nt]);
      }
    }
    const int t0 = bid * 64 + wid * 16 + quad * 4;
    if (m < 2) {
      u16* dst = (m == 0) ? qw : kw;
#pragma unroll
      for (int nt = 0; nt < 8; ++nt) {
        const int d = nt * 16 + l15;
#pragma unroll
        for (int r = 0; r < 4; ++r) dst[(t0 + r) * 128 + d] = f2b(acc[nt][r]);
      }
    } else {
      const int g = bid >> 5;
      const int p0 = t0 & 2047;
#pragma unroll
      for (int nt = 0; nt < 8; ++nt) {
        const int d = nt * 16 + l15;
        ushort4 hv = make_ushort4(f2b(acc[nt][0]), f2b(acc[nt][1]),
                                  f2b(acc[nt][2]), f2b(acc[nt][3]));
        *(ushort4*)&vbuf[g * 262144 + d * 2048 + p0] = hv;
      }
    }
    __syncthreads();
  }
}

// ---------------- kernel 2: flash attention per (window, 64-row Q tile) ----------------
__global__ __launch_bounds__(256, 2)
void k_attn(const u16* __restrict__ qw, const u16* __restrict__ kw,
            const u16* __restrict__ vbuf, const float* __restrict__ mask,
            u16* __restrict__ aout) {
  __shared__ __align__(16) u16 Qt[64 * 136];
  __shared__ __align__(16) u16 Kt[64 * 136];
  __shared__ __align__(16) u16 Vt[128 * 72];   // transposed V tile [d][key]
  __shared__ __align__(16) u16 Pt[4 * 16 * 72];  // per-wave P buffer
  const int tid = threadIdx.x;
  const int lane = tid & 63, wid = tid >> 6;
  const int l15 = lane & 15, quad = lane >> 4;
  const int bid = blockIdx.x;
  const int g = bid >> 5, qb = bid & 31;
  const u16* qbase = qw + g * 262144 + qb * 8192;
  const u16* kbase = kw + g * 262144;
  const u16* vbase = vbuf + g * 262144;
  const float* mbase = mask + (g & 3) * 4194304;

  {  // stage Q once
    const int row = tid >> 2, part = tid & 3;
    const uint4* sp = (const uint4*)(qbase + row * 128 + part * 32);
    uint4* dp = (uint4*)&Qt[row * 136 + part * 32];
#pragma unroll
    for (int q = 0; q < 4; ++q) dp[q] = sp[q];
  }
  __syncthreads();
  bf16x8 qfrag[4];
  const int arow = wid * 16 + l15;
#pragma unroll
  for (int kk = 0; kk < 4; ++kk)
    qfrag[kk] = *(const bf16x8*)&Qt[arow * 136 + kk * 32 + quad * 8];

  const f32x4 fz = {0.f, 0.f, 0.f, 0.f};
  f32x4 o[8];
#pragma unroll
  for (int nt = 0; nt < 8; ++nt) o[nt] = fz;
  float mrun[4] = {-1e30f, -1e30f, -1e30f, -1e30f};
  float lrun[4] = {0.f, 0.f, 0.f, 0.f};
  const int qrow0 = qb * 64 + wid * 16 + quad * 4;  // window-local q row (r=0)
  const float scale = 0.08838834764831845f;         // 1/sqrt(128)
  const float L2E = 1.4426950408889634f;

#pragma unroll 1
  for (int kt = 0; kt < 32; ++kt) {
    __syncthreads();  // protect K/V tiles from previous iteration's readers
    {  // stage K tile [key][d]
      const int row = tid >> 2, part = tid & 3;
      const uint4* sp = (const uint4*)(kbase + (kt * 64 + row) * 128 + part * 32);
      uint4* dp = (uint4*)&Kt[row * 136 + part * 32];
#pragma unroll
      for (int q = 0; q < 4; ++q) dp[q] = sp[q];
    }
    {  // stage Vt tile [d][key]
      const int dd = tid >> 1, half = tid & 1;
      const uint4* sp = (const uint4*)(vbase + dd * 2048 + kt * 64 + half * 32);
      uint4* dp = (uint4*)&Vt[dd * 72 + half * 32];
#pragma unroll
      for (int q = 0; q < 4; ++q) dp[q] = sp[q];
    }
    __syncthreads();

    // S = Q K^T  (16 q-rows x 64 keys per wave)
    f32x4 s[4];
#pragma unroll
    for (int nt = 0; nt < 4; ++nt) s[nt] = fz;
#pragma unroll
    for (int kk = 0; kk < 4; ++kk) {
#pragma unroll
      for (int nt = 0; nt < 4; ++nt) {
        bf16x8 bfr = *(const bf16x8*)&Kt[(nt * 16 + l15) * 136 + kk * 32 + quad * 8];
        s[nt] = MFMA(qfrag[kk], bfr, s[nt]);
      }
    }
    // scale + additive window mask
#pragma unroll
    for (int nt = 0; nt < 4; ++nt) {
      const int kc = kt * 64 + nt * 16 + l15;
#pragma unroll
      for (int r = 0; r < 4; ++r)
        s[nt][r] = fmaf(s[nt][r], scale, mbase[(qrow0 + r) * 2048 + kc]);
    }
    // online softmax (row spread over 16 lanes of this quad)
    float mx[4], rs[4];
#pragma unroll
    for (int r = 0; r < 4; ++r)
      mx[r] = fmaxf(fmaxf(s[0][r], s[1][r]), fmaxf(s[2][r], s[3][r]));
#pragma unroll
    for (int off = 1; off < 16; off <<= 1) {
#pragma unroll
      for (int r = 0; r < 4; ++r) mx[r] = fmaxf(mx[r], __shfl_xor(mx[r], off, 16));
    }
#pragma unroll
    for (int r = 0; r < 4; ++r) {
      const float mn = fmaxf(mrun[r], mx[r]);
      const float al = exp2f((mrun[r] - mn) * L2E);
      mrun[r] = mn;
      lrun[r] *= al;
      rs[r] = 0.f;
#pragma unroll
      for (int nt = 0; nt < 8; ++nt) o[nt][r] *= al;
#pragma unroll
      for (int nt = 0; nt < 4; ++nt) {
        const float p = exp2f((s[nt][r] - mn) * L2E);
        rs[r] += p;
        Pt[(wid * 16 + quad * 4 + r) * 72 + nt * 16 + l15] = f2b(p);  // C->LDS
      }
    }
#pragma unroll
    for (int off = 1; off < 16; off <<= 1) {
#pragma unroll
      for (int r = 0; r < 4; ++r) rs[r] += __shfl_xor(rs[r], off, 16);
    }
#pragma unroll
    for (int r = 0; r < 4; ++r) lrun[r] += rs[r];

    // O += P @ V  (P re-read in A-operand layout; per-wave buffer, in-order DS)
    bf16x8 pfrag[2];
#pragma unroll
    for (int kk = 0; kk < 2; ++kk)
      pfrag[kk] = *(const bf16x8*)&Pt[(wid * 16 + l15) * 72 + kk * 32 + quad * 8];
#pragma unroll
    for (int nt = 0; nt < 8; ++nt) {
#pragma unroll
      for (int kk = 0; kk < 2; ++kk) {
        bf16x8 bfr = *(const bf16x8*)&Vt[(nt * 16 + l15) * 72 + kk * 32 + quad * 8];
        o[nt] = MFMA(pfrag[kk], bfr, o[nt]);
      }
    }
  }

  // epilogue: normalize + scatter back to merged spatial layout (inverse window)
  const int b = g >> 2, wi = (g >> 1) & 1, wj = g & 1;
#pragma unroll
  for (int r = 0; r < 4; ++r) {
    const float inv = 1.f / lrun[r];
    const int p = qrow0 + r;
    const int ii = p >> 6, jj = p & 63;
    const int y = (wi * 32 + ii + 16) & 63;
    const int x = (wj * 64 + jj + 32) & 127;
    u16* op = aout + (b * 8192 + y * 128 + x) * 128;
#pragma unroll
    for (int nt = 0; nt < 8; ++nt) op[nt * 16 + l15] = f2b(o[nt][r] * inv);
  }
}

// ---------------- kernel 3: message @ Wm + LayerNorm(g1,b1) -> msg1 bf16 ----------------
__global__ __launch_bounds__(256, 2)
void k_wmln(const u16* __restrict__ ain, const u16* __restrict__ wmt,
            const float* __restrict__ g1, const float* __restrict__ b1,
            u16* __restrict__ msg1) {
  __shared__ __align__(16) u16 At[64 * 136];
  __shared__ __align__(16) u16 Bt[128 * 136];
  const int tid = threadIdx.x, bid = blockIdx.x;
  const int lane = tid & 63, wid = tid >> 6;
  const int l15 = lane & 15, quad = lane >> 4;
  {
    const int row = tid >> 2, part = tid & 3;
    const uint4* sp = (const uint4*)(ain + (bid * 64 + row) * 128 + part * 32);
    uint4* dp = (uint4*)&At[row * 136 + part * 32];
#pragma unroll
    for (int q = 0; q < 4; ++q) dp[q] = sp[q];
  }
  {
    const int n = tid >> 1, half = tid & 1;
    const uint4* sp = (const uint4*)(wmt + n * 128 + half * 64);
    uint4* dp = (uint4*)&Bt[n * 136 + half * 64];
#pragma unroll
    for (int q = 0; q < 8; ++q) dp[q] = sp[q];
  }
  __syncthreads();
  bf16x8 afrag[4];
  const int arow = wid * 16 + l15;
#pragma unroll
  for (int kk = 0; kk < 4; ++kk)
    afrag[kk] = *(const bf16x8*)&At[arow * 136 + kk * 32 + quad * 8];
  const f32x4 fz = {0.f, 0.f, 0.f, 0.f};
  f32x4 acc[8];
#pragma unroll
  for (int nt = 0; nt < 8; ++nt) acc[nt] = fz;
#pragma unroll
  for (int kk = 0; kk < 4; ++kk) {
#pragma unroll
    for (int nt = 0; nt < 8; ++nt) {
      bf16x8 bfr = *(const bf16x8*)&Bt[(nt * 16 + l15) * 136 + kk * 32 + quad * 8];
      acc[nt] = MFMA(afrag[kk], bfr, acc[nt]);
    }
  }
  float sum[4] = {0, 0, 0, 0}, sq[4] = {0, 0, 0, 0};
#pragma unroll
  for (int nt = 0; nt < 8; ++nt)
#pragma unroll
    for (int r = 0; r < 4; ++r) {
      const float v = acc[nt][r];
      sum[r] += v;
      sq[r] += v * v;
    }
#pragma unroll
  for (int off = 1; off < 16; off <<= 1)
#pragma unroll
    for (int r = 0; r < 4; ++r) {
      sum[r] += __shfl_xor(sum[r], off, 16);
      sq[r] += __shfl_xor(sq[r], off, 16);
    }
  float mean[4], rstd[4];
#pragma unroll
  for (int r = 0; r < 4; ++r) {
    mean[r] = sum[r] * (1.f / 128.f);
    const float var = sq[r] * (1.f / 128.f) - mean[r] * mean[r];
    rstd[r] = rsqrtf(var + 1e-5f);
  }
  const int t0 = bid * 64 + wid * 16 + quad * 4;
#pragma unroll
  for (int nt = 0; nt < 8; ++nt) {
    const int d = nt * 16 + l15;
    const float gg = g1[d], bb = b1[d];
#pragma unroll
    for (int r = 0; r < 4; ++r)
      msg1[(t0 + r) * 128 + d] = f2b((acc[nt][r] - mean[r]) * rstd[r] * gg + bb);
  }
}

// ---------------- kernel 4: gelu([src||msg1] @ W1) -> hidden bf16 ----------------
__global__ __launch_bounds__(256, 2)
void k_mlp1(const u16* __restrict__ srcb, const u16* __restrict__ msg1,
            const u16* __restrict__ w1t, u16* __restrict__ hid) {
  __shared__ __align__(16) u16 At[64 * 72];
  __shared__ __align__(16) u16 Bt[256 * 72];
  const int tid = threadIdx.x, bid = blockIdx.x;
  const int rb = bid >> 2, nb = bid & 3;
  const int lane = tid & 63, wid = tid >> 6;
  const int l15 = lane & 15, quad = lane >> 4;
  const f32x4 fz = {0.f, 0.f, 0.f, 0.f};
  f32x4 acc[16];
#pragma unroll
  for (int nt = 0; nt < 16; ++nt) acc[nt] = fz;
#pragma unroll 1
  for (int kc = 0; kc < 4; ++kc) {  // K chunks: src[0:64],src[64:128],msg[0:64],msg[64:128]
    __syncthreads();
    {
      const int row = tid >> 2, part = tid & 3;
      const u16* sp0 = (kc < 2) ? srcb : msg1;
      const uint4* sp = (const uint4*)(sp0 + (rb * 64 + row) * 128 + (kc & 1) * 64 + part * 16);
      uint4* dp = (uint4*)&At[row * 72 + part * 16];
      dp[0] = sp[0];
      dp[1] = sp[1];
    }
    {
      const uint4* sp = (const uint4*)(w1t + (nb * 256 + tid) * 256 + kc * 64);
      uint4* dp = (uint4*)&Bt[tid * 72];
#pragma unroll
      for (int q = 0; q < 8; ++q) dp[q] = sp[q];
    }
    __syncthreads();
#pragma unroll
    for (int kk = 0; kk < 2; ++kk) {
      bf16x8 a = *(const bf16x8*)&At[(wid * 16 + l15) * 72 + kk * 32 + quad * 8];
#pragma unroll
      for (int nt = 0; nt < 16; ++nt) {
        bf16x8 b = *(const bf16x8*)&Bt[(nt * 16 + l15) * 72 + kk * 32 + quad * 8];
        acc[nt] = MFMA(a, b, acc[nt]);
      }
    }
  }
  const int t0 = rb * 64 + wid * 16 + quad * 4;
#pragma unroll
  for (int nt = 0; nt < 16; ++nt) {
    const int n = nb * 256 + nt * 16 + l15;
#pragma unroll
    for (int r = 0; r < 4; ++r) {
      const float x = acc[nt][r];
      const float y = 0.5f * x * (1.f + erff(x * 0.70710678118654752f));  // exact gelu
      hid[(t0 + r) * 1024 + n] = f2b(y);
    }
  }
}

// ---------------- kernel 5: hidden @ W2 + LN(g2,b2) + residual -> out fp32 ----------------
__global__ __launch_bounds__(256, 2)
void k_mlp2(const u16* __restrict__ hid, const u16* __restrict__ w2t,
            const float* __restrict__ g2, const float* __restrict__ b2,
            const float* __restrict__ src, float* __restrict__ out) {
  __shared__ __align__(16) u16 At[64 * 72];
  __shared__ __align__(16) u16 Bt[128 * 72];
  const int tid = threadIdx.x, bid = blockIdx.x;
  const int lane = tid & 63, wid = tid >> 6;
  const int l15 = lane & 15, quad = lane >> 4;
  const f32x4 fz = {0.f, 0.f, 0.f, 0.f};
  f32x4 acc[8];
#pragma unroll
  for (int nt = 0; nt < 8; ++nt) acc[nt] = fz;
#pragma unroll 1
  for (int kc = 0; kc < 16; ++kc) {
    __syncthreads();
    {
      const int row = tid >> 2, part = tid & 3;
      const uint4* sp = (const uint4*)(hid + (bid * 64 + row) * 1024 + kc * 64 + part * 16);
      uint4* dp = (uint4*)&At[row * 72 + part * 16];
      dp[0] = sp[0];
      dp[1] = sp[1];
    }
    {
      const int n = tid >> 1, half = tid & 1;
      const uint4* sp = (const uint4*)(w2t + n * 1024 + kc * 64 + half * 32);
      uint4* dp = (uint4*)&Bt[n * 72 + half * 32];
#pragma unroll
      for (int q = 0; q < 4; ++q) dp[q] = sp[q];
    }
    __syncthreads();
#pragma unroll
    for (int kk = 0; kk < 2; ++kk) {
      bf16x8 a = *(const bf16x8*)&At[(wid * 16 + l15) * 72 + kk * 32 + quad * 8];
#pragma unroll
      for (int nt = 0; nt < 8; ++nt) {
        bf16x8 b = *(const bf16x8*)&Bt[(nt * 16 + l15) * 72 + kk * 32 + quad * 8];
        acc[nt] = MFMA(a, b, acc[nt]);
      }
    }
  }
  float sum[4] = {0, 0, 0, 0}, sq[4] = {0, 0, 0, 0};
#pragma unroll
  for (int nt = 0; nt < 8; ++nt)
#pragma unroll
    for (int r = 0; r < 4; ++r) {
      const float v = acc[nt][r];
      sum[r] += v;
      sq[r] += v * v;
    }
#pragma unroll
  for (int off = 1; off < 16; off <<= 1)
#pragma unroll
    for (int r = 0; r < 4; ++r) {
      sum[r] += __shfl_xor(sum[r], off, 16);
      sq[r] += __shfl_xor(sq[r], off, 16);
    }
  float mean[4], rstd[4];
#pragma unroll
  for (int r = 0; r < 4; ++r) {
    mean[r] = sum[r] * (1.f / 128.f);
    const float var = sq[r] * (1.f / 128.f) - mean[r] * mean[r];
    rstd[r] = rsqrtf(var + 1e-5f);
  }
  const int t0 = bid * 64 + wid * 16 + quad * 4;
#pragma unroll
  for (int nt = 0; nt < 8; ++nt) {
    const int d = nt * 16 + l15;
    const float gg = g2[d], bb = b2[d];
#pragma unroll
    for (int r = 0; r < 4; ++r) {
      const int idx = (t0 + r) * 128 + d;
      out[idx] = src[idx] + (acc[nt][r] - mean[r]) * rstd[r] * gg + bb;
    }
  }
}

extern "C" void kernel_launch(void* const* d_in, const int* in_sizes, int n_in,
                              void* d_out, int out_size, void* d_ws, size_t ws_size,
                              hipStream_t stream) {
  const float* src  = (const float*)d_in[0];
  const float* mask = (const float*)d_in[2];
  const float* Wq = (const float*)d_in[8];
  const float* Wk = (const float*)d_in[9];
  const float* Wv = (const float*)d_in[10];
  const float* Wm = (const float*)d_in[11];
  const float* g1 = (const float*)d_in[12];
  const float* b1 = (const float*)d_in[13];
  const float* W1 = (const float*)d_in[14];
  const float* W2 = (const float*)d_in[15];
  const float* g2 = (const float*)d_in[16];
  const float* b2 = (const float*)d_in[17];
  char* ws = (char*)d_ws;
  u16* qw   = (u16*)(ws + QW_OFF);
  u16* kw   = (u16*)(ws + KW_OFF);
  u16* vbuf = (u16*)(ws + VBUF_OFF);
  u16* ao   = (u16*)(ws + AO_OFF);
  u16* hid  = (u16*)(ws + HID_OFF);
  u16* srcb = (u16*)(ws + SRCB_OFF);
  u16* msg1 = (u16*)(ws + MSG1_OFF);
  u16* wqt = (u16*)(ws + WQT_OFF);
  u16* wkt = (u16*)(ws + WKT_OFF);
  u16* wvt = (u16*)(ws + WVT_OFF);
  u16* wmt = (u16*)(ws + WMT_OFF);
  u16* w1t = (u16*)(ws + W1T_OFF);
  u16* w2t = (u16*)(ws + W2T_OFF);

  k_prep<<<1792, 256, 0, stream>>>(Wq, Wk, Wv, Wm, W1, W2, wqt, wkt, wvt, wmt, w1t, w2t);
  k_qkv<<<512, 256, 0, stream>>>(src, wqt, wkt, wvt, qw, kw, vbuf, srcb);
  k_attn<<<512, 256, 0, stream>>>(qw, kw, vbuf, mask, ao);
  k_wmln<<<512, 256, 0, stream>>>(ao, wmt, g1, b1, msg1);
  k_mlp1<<<2048, 256, 0, stream>>>(srcb, msg1, w1t, hid);
  k_mlp2<<<512, 256, 0, stream>>>(hid, w2t, g2, b2, src, (float*)d_out);
}